// Round 7
// baseline (1601.690 us; speedup 1.0000x reference)
//
#include <hip/hip_runtime.h>
#include <math.h>

typedef __bf16 bf16;
typedef __attribute__((ext_vector_type(8))) __bf16 bf16x8;
typedef __attribute__((ext_vector_type(4))) float f32x4;

#define N_SEQ 4096
#define NEGINF -1e30f

// async global->LDS, 16B per lane. LDS dest is wave-uniform base + lane*16;
// global src is per-lane (carries the inverse swizzle).
__device__ __forceinline__ void gl_lds16(const void* g, void* l) {
    __builtin_amdgcn_global_load_lds(
        (const __attribute__((address_space(1))) void*)g,
        (__attribute__((address_space(3))) void*)l, 16, 0, 0);
}

// read one MFMA fragment (8 contiguous bf16) from a [rows][64] bf16 LDS tile
// stored with granule XOR swizzle: granule position p holds original granule
// p ^ (row&7).
__device__ __forceinline__ bf16x8 frag64(const bf16* base, int row, int g) {
    return *(const bf16x8*)(base + (row << 6) + ((g ^ (row & 7)) << 3));
}

// ---------------------------------------------------------------------------
// merged prep: blocks [0,2048): cast x fp32[8192][512] -> bf16 (8 elem/thr)
//              blocks [2048,2304): transpose+cast weights into Wcat [2048][512]
//              (= [Wq^T; Wk^T; Wv^T; Wfc^T]) and bcat fp32 [2048].
// ---------------------------------------------------------------------------
__global__ __launch_bounds__(256) void prep_k(
    const float* __restrict__ x, bf16* __restrict__ xb,
    const float* __restrict__ Wq, const float* __restrict__ bq,
    const float* __restrict__ Wk, const float* __restrict__ bk,
    const float* __restrict__ Wv, const float* __restrict__ bv,
    const float* __restrict__ Wfc, const float* __restrict__ bfc,
    bf16* __restrict__ Wcat, float* __restrict__ bcat) {
    __shared__ bf16 tile[64][65];
    const int t = threadIdx.x;
    const int bx = blockIdx.x;
    if (bx < 2048) {
        int idx = bx * 256 + t;
        const float4* xv = (const float4*)x;
        float4 a = xv[idx * 2], b = xv[idx * 2 + 1];
        bf16x8 o;
        o[0] = (bf16)a.x; o[1] = (bf16)a.y; o[2] = (bf16)a.z; o[3] = (bf16)a.w;
        o[4] = (bf16)b.x; o[5] = (bf16)b.y; o[6] = (bf16)b.z; o[7] = (bf16)b.w;
        ((bf16x8*)xb)[idx] = o;
        return;
    }
    const int bz = bx - 2048;             // 0..255
    const int k0 = (bz & 7) << 6, n0 = (bz >> 3) << 6;
    const int sel = n0 >> 9, nloc = n0 & 511;
    const float* W = (sel == 0) ? Wq : (sel == 1) ? Wk : (sel == 2) ? Wv : Wfc;
    const float* bi = (sel == 0) ? bq : (sel == 1) ? bk : (sel == 2) ? bv : bfc;
#pragma unroll
    for (int i = 0; i < 16; i++) {
        int idx = (i << 8) + t;
        int r = idx >> 6, c = idx & 63;
        tile[r][c] = (bf16)W[(size_t)(k0 + r) * 512 + nloc + c];
    }
    __syncthreads();
#pragma unroll
    for (int i = 0; i < 16; i++) {
        int idx = (i << 8) + t;
        int r = idx >> 6, c = idx & 63;
        Wcat[(size_t)(n0 + r) * 512 + k0 + c] = tile[c][r];
    }
    if ((bz & 7) == 0 && t < 64) bcat[n0 + t] = bi[nloc + t];
}

// ---------------------------------------------------------------------------
// bf16 MFMA GEMM (m97 structure) + REP instrumentation loop (idempotent:
// acc re-zeroed, same stores each rep; rep-top barrier orders LDS reuse).
// ---------------------------------------------------------------------------
template <int OUT, int BN, int NT, int REP>
__global__ __launch_bounds__(256, 3) void gemm_bf16_k(
    const bf16* __restrict__ A, const bf16* __restrict__ Bt,
    const float* __restrict__ bias, void* __restrict__ Cout) {
    constexpr int NI = BN / 32;
    __shared__ __align__(16) bf16 smem[16384];  // 32 KB
    bf16* sA = smem;          // [128][64]
    bf16* sB = smem + 8192;   // [BN][64]
    const int t = threadIdx.x;
    const int lane = t & 63, wid = t >> 6;
    const int wr = wid >> 1, wc = wid & 1;
    const int wg = blockIdx.x;
    const int s = (wg & 7) * (8 * NT) + (wg >> 3);  // XCD swizzle (grid%8==0)
    const int m_idx = s / NT, n_idx = s - m_idx * NT;
    const int m0 = m_idx << 7, n0 = n_idx * BN;

    const bf16* Ag = A + ((size_t)m0 << 9);
    const bf16* Bg = Bt + ((size_t)n0 << 9);

#pragma unroll 1
    for (int rep = 0; rep < REP; rep++) {
        __syncthreads();  // prior rep's epilogue LDS reads complete
        f32x4 acc[4][NI] = {};

        for (int kt = 0; kt < 8; kt++) {
            const int k0 = kt << 6;
#pragma unroll
            for (int i = 0; i < 4; i++) {
                int gid = (i << 8) + t;
                int row = gid >> 3, gs = ((gid & 7) ^ (row & 7)) << 3;
                gl_lds16(Ag + ((size_t)row << 9) + k0 + gs, &sA[gid << 3]);
            }
#pragma unroll
            for (int i = 0; i < NI; i++) {
                int gid = (i << 8) + t;
                int row = gid >> 3, gs = ((gid & 7) ^ (row & 7)) << 3;
                gl_lds16(Bg + ((size_t)row << 9) + k0 + gs, &sB[gid << 3]);
            }
            __syncthreads();  // drains vmcnt -> tile ready
#pragma unroll
            for (int ks = 0; ks < 2; ks++) {
                int g = (ks << 2) + (lane >> 4);
                bf16x8 af[4], bfr[NI];
#pragma unroll
                for (int mi = 0; mi < 4; mi++)
                    af[mi] = frag64(sA, (wr << 6) + (mi << 4) + (lane & 15), g);
#pragma unroll
                for (int ni = 0; ni < NI; ni++)
                    bfr[ni] =
                        frag64(sB, wc * (BN / 2) + (ni << 4) + (lane & 15), g);
#pragma unroll
                for (int mi = 0; mi < 4; mi++)
#pragma unroll
                    for (int ni = 0; ni < NI; ni++)
                        acc[mi][ni] = __builtin_amdgcn_mfma_f32_16x16x32_bf16(
                            af[mi], bfr[ni], acc[mi][ni], 0, 0, 0);
            }
            __syncthreads();  // readers done before next overwrite
        }

        float bb[NI];
#pragma unroll
        for (int ni = 0; ni < NI; ni++)
            bb[ni] = bias[n0 + wc * (BN / 2) + (ni << 4) + (lane & 15)];

        if (OUT == 0) {
            bf16* cs = smem;
#pragma unroll
            for (int mi = 0; mi < 4; mi++)
#pragma unroll
                for (int ni = 0; ni < NI; ni++)
#pragma unroll
                    for (int r = 0; r < 4; r++) {
                        int row = (wr << 6) + (mi << 4) + ((lane >> 4) << 2) + r;
                        int col = (wc << 6) + (ni << 4) + (lane & 15);
                        int g = col >> 3;
                        cs[(row << 7) + ((g ^ (row & 7)) << 3) + (col & 7)] =
                            (bf16)(acc[mi][ni][r] + bb[ni]);
                    }
            __syncthreads();
            int row = t >> 1, half = t & 1;
            int gm = m0 + row;
            int b = gm >> 12, n = gm & 4095;
#pragma unroll
            for (int j = 0; j < 8; j++) {
                int g = (half << 3) + j;
                bf16x8 v = *(bf16x8*)&cs[(row << 7) + ((g ^ (row & 7)) << 3)];
                int gc = n0 + (g << 3);
                int sel = gc >> 9, rem = gc & 511;
                int h = rem >> 6, d = rem & 63;
                *(bf16x8*)&(((bf16*)Cout)[(((size_t)((sel << 4) + (b << 3) + h) *
                                                4096 +
                                            n)
                                           << 6) +
                                          d]) = v;
            }
        } else {
            float* cs = (float*)smem;
#pragma unroll
            for (int mi = 0; mi < 4; mi++)
#pragma unroll
                for (int ni = 0; ni < NI; ni++)
#pragma unroll
                    for (int r = 0; r < 4; r++) {
                        int row = (wr << 6) + (mi << 4) + ((lane >> 4) << 2) + r;
                        int col = (wc << 5) + (ni << 4) + (lane & 15);
                        int g4 = col >> 2;
                        cs[(row << 6) + ((g4 ^ (row & 7)) << 2) + (col & 3)] =
                            acc[mi][ni][r] + bb[ni];
                    }
            __syncthreads();
            int row = t >> 1, half = t & 1;
#pragma unroll
            for (int j = 0; j < 8; j++) {
                int g4 = (half << 3) + j;
                f32x4 v = *(f32x4*)&cs[(row << 6) + ((g4 ^ (row & 7)) << 2)];
                *(f32x4*)&(
                    ((float*)Cout)[(size_t)(m0 + row) * 512 + n0 + (g4 << 2)]) =
                    v;
            }
        }
    }
}

// ---------------------------------------------------------------------------
// Windowed flash attention + REP instrumentation loop (idempotent).
// ---------------------------------------------------------------------------
template <int REP>
__global__ __launch_bounds__(256) void attn_bf16_k(
    const bf16* __restrict__ Q, const bf16* __restrict__ K,
    const bf16* __restrict__ V, bf16* __restrict__ O) {
    __shared__ bf16 QP[8192];      // Q tile [128][64]; reused as P bands
    __shared__ bf16 Ks[2][4096];   // K chunk [key][64], swizzled, dbuf
    __shared__ bf16 VT[2][4096];   // V chunk transposed [d][key], swizzled, dbuf

    const int t = threadIdx.x;
    const int lane = t & 63, wid = t >> 6;
    const int wg = blockIdx.x;
    const int sblk = ((wg & 7) << 6) + (wg >> 3);  // XCD swizzle (512%8==0)
    const int bh = sblk >> 5;
    const int q0 = (sblk & 31) << 7;

    const bf16* Qp = Q + ((size_t)bh << 18);
    const bf16* Kp = K + ((size_t)bh << 18);
    const bf16* Vp = V + ((size_t)bh << 18);

    const int cstart = (q0 >= 128) ? q0 - 128 : 0;
    const int cend = (q0 + 256 <= N_SEQ) ? q0 + 256 : N_SEQ;
    const int nch = (cend - cstart) >> 6;

#define STAGE_KV(c0, sb)                                                     \
    {                                                                        \
        _Pragma("unroll") for (int i = 0; i < 2; i++) {                      \
            int gid = (i << 8) + t;                                          \
            int row = gid >> 3, gs = ((gid & 7) ^ (row & 7)) << 3;           \
            gl_lds16(Kp + ((size_t)((c0) + row) << 6) + gs,                  \
                     &Ks[sb][gid << 3]);                                     \
        }                                                                    \
        int key = t >> 2;                                                    \
        int gd0 = (t & 3) << 1;                                              \
        const uint4* vs = (const uint4*)(Vp + ((size_t)((c0) + key) << 6));  \
        union { uint4 u; bf16 h[8]; } u0, u1;                                \
        u0.u = vs[gd0]; u1.u = vs[gd0 + 1];                                  \
        _Pragma("unroll") for (int e = 0; e < 8; e++) {                      \
            int d0 = (gd0 << 3) + e;                                         \
            VT[sb][(d0 << 6) + (((key >> 3) ^ (d0 & 7)) << 3) + (key & 7)] = \
                u0.h[e];                                                     \
            int d1 = d0 + 8;                                                 \
            VT[sb][(d1 << 6) + (((key >> 3) ^ (d1 & 7)) << 3) + (key & 7)] = \
                u1.h[e];                                                     \
        }                                                                    \
    }

#pragma unroll 1
    for (int rep = 0; rep < REP; rep++) {
        __syncthreads();  // prior rep's P-band/K/V readers complete

#pragma unroll
        for (int i = 0; i < 4; i++) {
            int gid = (i << 8) + t;
            int row = gid >> 3, gs = ((gid & 7) ^ (row & 7)) << 3;
            gl_lds16(Qp + ((size_t)(q0 + row) << 6) + gs, &QP[gid << 3]);
        }
        __syncthreads();

        bf16x8 aq[2][2];
#pragma unroll
        for (int b = 0; b < 2; b++)
#pragma unroll
            for (int ks = 0; ks < 2; ks++)
                aq[b][ks] = frag64(QP, (wid << 5) + (b << 4) + (lane & 15),
                                   (ks << 2) + (lane >> 4));

        float mrun[2][4], lrun[2][4];
        f32x4 acc_o[2][4] = {};
#pragma unroll
        for (int b = 0; b < 2; b++)
#pragma unroll
            for (int r = 0; r < 4; r++) {
                mrun[b][r] = NEGINF;
                lrun[b][r] = 0.f;
            }

        STAGE_KV(cstart, 0);

        int buf = 0;
        for (int tch = 0; tch < nch; tch++) {
            const int c0 = cstart + (tch << 6);
            __syncthreads();
            if (tch + 1 < nch) STAGE_KV(c0 + 64, buf ^ 1);

            const int rel = c0 - q0;
            const bool masked = (rel != 0) && (rel != 64);

#pragma unroll
            for (int b = 0; b < 2; b++) {
                f32x4 s[4] = {};
#pragma unroll
                for (int ks = 0; ks < 2; ks++) {
                    int g = (ks << 2) + (lane >> 4);
#pragma unroll
                    for (int ni = 0; ni < 4; ni++) {
                        bf16x8 bk =
                            frag64(&Ks[buf][0], (ni << 4) + (lane & 15), g);
                        s[ni] = __builtin_amdgcn_mfma_f32_16x16x32_bf16(
                            aq[b][ks], bk, s[ni], 0, 0, 0);
                    }
                }

                bf16* Pw = &QP[((wid << 1) + b) << 10];
#pragma unroll
                for (int r = 0; r < 4; r++) {
                    int rowl = ((lane >> 4) << 2) + r;
                    int qi = q0 + (wid << 5) + (b << 4) + rowl;
                    float v[4];
                    if (masked) {
#pragma unroll
                        for (int ni = 0; ni < 4; ni++) {
                            int kj = c0 + (ni << 4) + (lane & 15);
                            int dd = qi - kj;
                            v[ni] = (dd <= 128 && dd >= -128)
                                        ? s[ni][r] * 0.125f
                                        : NEGINF;
                        }
                    } else {
#pragma unroll
                        for (int ni = 0; ni < 4; ni++) v[ni] = s[ni][r] * 0.125f;
                    }
                    float mx = fmaxf(fmaxf(v[0], v[1]), fmaxf(v[2], v[3]));
#pragma unroll
                    for (int off = 1; off < 16; off <<= 1)
                        mx = fmaxf(mx, __shfl_xor(mx, off));
                    float mn = fmaxf(mrun[b][r], mx);
                    float alpha = __expf(mrun[b][r] - mn);
                    float rs = 0.f;
#pragma unroll
                    for (int ni = 0; ni < 4; ni++) {
                        float p = __expf(v[ni] - mn);
                        rs += p;
                        int col = (ni << 4) + (lane & 15);
                        Pw[(rowl << 6) + (((col >> 3) ^ (rowl & 7)) << 3) +
                           (col & 7)] = (bf16)p;
                    }
#pragma unroll
                    for (int off = 1; off < 16; off <<= 1)
                        rs += __shfl_xor(rs, off);
                    mrun[b][r] = mn;
                    lrun[b][r] = lrun[b][r] * alpha + rs;
#pragma unroll
                    for (int nd = 0; nd < 4; nd++) acc_o[b][nd][r] *= alpha;
                }

#pragma unroll
                for (int ks = 0; ks < 2; ks++) {
                    int g = (ks << 2) + (lane >> 4);
                    bf16x8 pa = frag64(Pw, lane & 15, g);
#pragma unroll
                    for (int nd = 0; nd < 4; nd++) {
                        bf16x8 bv =
                            frag64(&VT[buf][0], (nd << 4) + (lane & 15), g);
                        acc_o[b][nd] = __builtin_amdgcn_mfma_f32_16x16x32_bf16(
                            pa, bv, acc_o[b][nd], 0, 0, 0);
                    }
                }
            }
            buf ^= 1;
        }

        const int bb = bh >> 3, h = bh & 7;
#pragma unroll
        for (int b = 0; b < 2; b++) {
#pragma unroll
            for (int r = 0; r < 4; r++) {
                float inv = 1.f / lrun[b][r];
                int n = q0 + (wid << 5) + (b << 4) + ((lane >> 4) << 2) + r;
#pragma unroll
                for (int nd = 0; nd < 4; nd++) {
                    int d = (nd << 4) + (lane & 15);
                    O[(((size_t)(bb * 4096 + n)) << 9) + (h << 6) + d] =
                        (bf16)(acc_o[b][nd][r] * inv);
                }
            }
        }
    }
#undef STAGE_KV
}

extern "C" void kernel_launch(void* const* d_in, const int* in_sizes, int n_in,
                              void* d_out, int out_size, void* d_ws, size_t ws_size,
                              hipStream_t stream) {
    (void)in_sizes; (void)n_in; (void)out_size; (void)ws_size;
    const float* x   = (const float*)d_in[0];
    const float* Wq  = (const float*)d_in[1];
    const float* bq  = (const float*)d_in[2];
    const float* Wk  = (const float*)d_in[3];
    const float* bk  = (const float*)d_in[4];
    const float* Wv  = (const float*)d_in[5];
    const float* bv  = (const float*)d_in[6];
    const float* Wfc = (const float*)d_in[7];
    const float* bfc = (const float*)d_in[8];

    bf16* xb    = (bf16*)d_ws;                       // [8192][512]
    bf16* Wcat  = xb + (size_t)8192 * 512;           // [2048][512]
    float* bcat = (float*)(Wcat + (size_t)2048 * 512);  // [2048]
    bf16* QKVb  = (bf16*)(bcat + 2048);              // [3][16][4096][64]
    bf16* Ob    = QKVb + (size_t)3 * 16 * 4096 * 64; // [8192][512]

    prep_k<<<2304, 256, 0, stream>>>(x, xb, Wq, bq, Wk, bk, Wv, bv, Wfc, bfc,
                                     Wcat, bcat);

    // fused QKV: C[8192 x 1536]  (REP=16 instrumentation)
    gemm_bf16_k<0, 128, 12, 16><<<768, 256, 0, stream>>>(xb, Wcat, bcat, QKVb);

    const bf16* Qb = QKVb;
    const bf16* Kb = QKVb + ((size_t)1 << 22);
    const bf16* Vb = QKVb + ((size_t)2 << 22);
    attn_bf16_k<16><<<512, 256, 0, stream>>>(Qb, Kb, Vb, Ob);

    // fc: C[8192 x 512] fp32  (REP=16 instrumentation)
    gemm_bf16_k<1, 64, 8, 16><<<512, 256, 0, stream>>>(
        Ob, Wcat + ((size_t)1536 << 9), bcat + 1536, d_out);
}

// Round 8
// 153.688 us; speedup vs baseline: 10.4217x; 10.4217x over previous
//
#include <hip/hip_runtime.h>
#include <math.h>

typedef __bf16 bf16;
typedef __attribute__((ext_vector_type(8))) __bf16 bf16x8;
typedef __attribute__((ext_vector_type(4))) float f32x4;

#define N_SEQ 4096
#define NEGINF -1e30f

// async global->LDS, 16B per lane. LDS dest is wave-uniform base + lane*16;
// global src is per-lane (carries the inverse swizzle).
__device__ __forceinline__ void gl_lds16(const void* g, void* l) {
    __builtin_amdgcn_global_load_lds(
        (const __attribute__((address_space(1))) void*)g,
        (__attribute__((address_space(3))) void*)l, 16, 0, 0);
}

// read one MFMA fragment (8 contiguous bf16) from a [rows][64] bf16 LDS tile
// stored with granule XOR swizzle: granule position p holds original granule
// p ^ (row&7).
__device__ __forceinline__ bf16x8 frag64(const bf16* base, int row, int g) {
    return *(const bf16x8*)(base + (row << 6) + ((g ^ (row & 7)) << 3));
}

// ---------------------------------------------------------------------------
// merged prep: blocks [0,2048): cast x fp32[8192][512] -> bf16 (8 elem/thr)
//              blocks [2048,2304): transpose+cast weights into Wcat [2048][512]
//              (= [Wq^T; Wk^T; Wv^T; Wfc^T]) and bcat fp32 [2048].
// ---------------------------------------------------------------------------
__global__ __launch_bounds__(256) void prep_k(
    const float* __restrict__ x, bf16* __restrict__ xb,
    const float* __restrict__ Wq, const float* __restrict__ bq,
    const float* __restrict__ Wk, const float* __restrict__ bk,
    const float* __restrict__ Wv, const float* __restrict__ bv,
    const float* __restrict__ Wfc, const float* __restrict__ bfc,
    bf16* __restrict__ Wcat, float* __restrict__ bcat) {
    __shared__ bf16 tile[64][65];
    const int t = threadIdx.x;
    const int bx = blockIdx.x;
    if (bx < 2048) {
        int idx = bx * 256 + t;
        const float4* xv = (const float4*)x;
        float4 a = xv[idx * 2], b = xv[idx * 2 + 1];
        bf16x8 o;
        o[0] = (bf16)a.x; o[1] = (bf16)a.y; o[2] = (bf16)a.z; o[3] = (bf16)a.w;
        o[4] = (bf16)b.x; o[5] = (bf16)b.y; o[6] = (bf16)b.z; o[7] = (bf16)b.w;
        ((bf16x8*)xb)[idx] = o;
        return;
    }
    const int bz = bx - 2048;             // 0..255
    const int k0 = (bz & 7) << 6, n0 = (bz >> 3) << 6;
    const int sel = n0 >> 9, nloc = n0 & 511;
    const float* W = (sel == 0) ? Wq : (sel == 1) ? Wk : (sel == 2) ? Wv : Wfc;
    const float* bi = (sel == 0) ? bq : (sel == 1) ? bk : (sel == 2) ? bv : bfc;
#pragma unroll
    for (int i = 0; i < 16; i++) {
        int idx = (i << 8) + t;
        int r = idx >> 6, c = idx & 63;
        tile[r][c] = (bf16)W[(size_t)(k0 + r) * 512 + nloc + c];
    }
    __syncthreads();
#pragma unroll
    for (int i = 0; i < 16; i++) {
        int idx = (i << 8) + t;
        int r = idx >> 6, c = idx & 63;
        Wcat[(size_t)(n0 + r) * 512 + k0 + c] = tile[c][r];
    }
    if ((bz & 7) == 0 && t < 64) bcat[n0 + t] = bi[nloc + t];
}

// ---------------------------------------------------------------------------
// bf16 MFMA GEMM (m97 structure): C[8192 x Nc] = A[8192 x 512] * Bt^T (+bias)
// Tile 128 x BN, BK=64, single-buffered 32KB LDS, gl_lds(16B), XOR granule
// swizzle, 2 barriers/K-step, 4 waves (2x2), 16x16x32 MFMA, XCD swizzle.
// OUT 0 (QKV): n0<1024 -> Q,K head-split bf16 [sel][16][4096][64];
//              n0>=1024 -> V TRANSPOSED: VTg [16 bh][64 d][4096 n] bf16.
// OUT 1: fp32 row-major [m][512].
// ---------------------------------------------------------------------------
template <int OUT, int BN, int NT>
__global__ __launch_bounds__(256, 3) void gemm_bf16_k(
    const bf16* __restrict__ A, const bf16* __restrict__ Bt,
    const float* __restrict__ bias, void* __restrict__ Cout,
    bf16* __restrict__ VTg) {
    constexpr int NI = BN / 32;
    __shared__ __align__(16) bf16 smem[16384];  // 32 KB
    bf16* sA = smem;          // [128][64]
    bf16* sB = smem + 8192;   // [BN][64]
    const int t = threadIdx.x;
    const int lane = t & 63, wid = t >> 6;
    const int wr = wid >> 1, wc = wid & 1;
    const int wg = blockIdx.x;
    const int s = (wg & 7) * (8 * NT) + (wg >> 3);  // XCD swizzle (grid%8==0)
    const int m_idx = s / NT, n_idx = s - m_idx * NT;
    const int m0 = m_idx << 7, n0 = n_idx * BN;

    f32x4 acc[4][NI] = {};

    const bf16* Ag = A + ((size_t)m0 << 9);
    const bf16* Bg = Bt + ((size_t)n0 << 9);

    for (int kt = 0; kt < 8; kt++) {
        const int k0 = kt << 6;
#pragma unroll
        for (int i = 0; i < 4; i++) {
            int gid = (i << 8) + t;
            int row = gid >> 3, gs = ((gid & 7) ^ (row & 7)) << 3;
            gl_lds16(Ag + ((size_t)row << 9) + k0 + gs, &sA[gid << 3]);
        }
#pragma unroll
        for (int i = 0; i < NI; i++) {
            int gid = (i << 8) + t;
            int row = gid >> 3, gs = ((gid & 7) ^ (row & 7)) << 3;
            gl_lds16(Bg + ((size_t)row << 9) + k0 + gs, &sB[gid << 3]);
        }
        __syncthreads();  // drains vmcnt -> tile ready
#pragma unroll
        for (int ks = 0; ks < 2; ks++) {
            int g = (ks << 2) + (lane >> 4);
            bf16x8 af[4], bfr[NI];
#pragma unroll
            for (int mi = 0; mi < 4; mi++)
                af[mi] = frag64(sA, (wr << 6) + (mi << 4) + (lane & 15), g);
#pragma unroll
            for (int ni = 0; ni < NI; ni++)
                bfr[ni] = frag64(sB, wc * (BN / 2) + (ni << 4) + (lane & 15), g);
#pragma unroll
            for (int mi = 0; mi < 4; mi++)
#pragma unroll
                for (int ni = 0; ni < NI; ni++)
                    acc[mi][ni] = __builtin_amdgcn_mfma_f32_16x16x32_bf16(
                        af[mi], bfr[ni], acc[mi][ni], 0, 0, 0);
        }
        __syncthreads();  // readers done before next overwrite
    }

    // bias (per n-frag, lane-resident)
    float bb[NI];
#pragma unroll
    for (int ni = 0; ni < NI; ni++)
        bb[ni] = bias[n0 + wc * (BN / 2) + (ni << 4) + (lane & 15)];

    if (OUT == 0) {
        if (n0 < 1024) {
            // Q/K tiles: LDS-bounce [128 m][128 col] swizzled -> coalesced
            bf16* cs = smem;
#pragma unroll
            for (int mi = 0; mi < 4; mi++)
#pragma unroll
                for (int ni = 0; ni < NI; ni++)
#pragma unroll
                    for (int r = 0; r < 4; r++) {
                        int row = (wr << 6) + (mi << 4) + ((lane >> 4) << 2) + r;
                        int col = (wc << 6) + (ni << 4) + (lane & 15);
                        int g = col >> 3;
                        cs[(row << 7) + ((g ^ (row & 7)) << 3) + (col & 7)] =
                            (bf16)(acc[mi][ni][r] + bb[ni]);
                    }
            __syncthreads();
            int row = t >> 1, half = t & 1;
            int gm = m0 + row;
            int b = gm >> 12, n = gm & 4095;
#pragma unroll
            for (int j = 0; j < 8; j++) {
                int g = (half << 3) + j;
                bf16x8 v = *(bf16x8*)&cs[(row << 7) + ((g ^ (row & 7)) << 3)];
                int gc = n0 + (g << 3);
                int sel = gc >> 9, rem = gc & 511;
                int h = rem >> 6, d = rem & 63;
                *(bf16x8*)&(((bf16*)Cout)[(((size_t)((sel << 4) + (b << 3) + h) *
                                                4096 +
                                            n)
                                           << 6) +
                                          d]) = v;
            }
        } else {
            // V tiles: transpose in LDS -> V^T [bh][d][4096] coalesced-ish
            bf16* cs = smem;  // cs[d' 0..127][n' 0..127], granule-swizzled n'
#pragma unroll
            for (int mi = 0; mi < 4; mi++)
#pragma unroll
                for (int ni = 0; ni < NI; ni++)
#pragma unroll
                    for (int r = 0; r < 4; r++) {
                        int row = (wr << 6) + (mi << 4) + ((lane >> 4) << 2) + r;  // n'
                        int col = (wc << 6) + (ni << 4) + (lane & 15);             // d'
                        cs[(col << 7) + (((row >> 3) ^ (col & 7)) << 3) +
                           (row & 7)] = (bf16)(acc[mi][ni][r] + bb[ni]);
                    }
            __syncthreads();
            int dp = t >> 1, half = t & 1;  // d' 0..127, n-half
            int rem = (n0 - 1024) + dp;     // 0..511
            int h = rem >> 6, d = rem & 63;
            int b = m0 >> 12;
            size_t rowbase =
                ((size_t)(((b << 3) + h) << 6) + d) * 4096 + (m0 & 4095);
#pragma unroll
            for (int j = 0; j < 8; j++) {
                int g = (half << 3) + j;  // n'-octet
                bf16x8 v = *(bf16x8*)&cs[(dp << 7) + ((g ^ (dp & 7)) << 3)];
                *(bf16x8*)&VTg[rowbase + (g << 3)] = v;
            }
        }
    } else {
        // fp32 row-major via LDS-bounce
        float* cs = (float*)smem;
#pragma unroll
        for (int mi = 0; mi < 4; mi++)
#pragma unroll
            for (int ni = 0; ni < NI; ni++)
#pragma unroll
                for (int r = 0; r < 4; r++) {
                    int row = (wr << 6) + (mi << 4) + ((lane >> 4) << 2) + r;
                    int col = (wc << 5) + (ni << 4) + (lane & 15);
                    int g4 = col >> 2;
                    cs[(row << 6) + ((g4 ^ (row & 7)) << 2) + (col & 3)] =
                        acc[mi][ni][r] + bb[ni];
                }
        __syncthreads();
        int row = t >> 1, half = t & 1;
#pragma unroll
        for (int j = 0; j < 8; j++) {
            int g4 = (half << 3) + j;
            f32x4 v = *(f32x4*)&cs[(row << 6) + ((g4 ^ (row & 7)) << 2)];
            *(f32x4*)&(
                ((float*)Cout)[(size_t)(m0 + row) * 512 + n0 + (g4 << 2)]) = v;
        }
    }
}

// ---------------------------------------------------------------------------
// Windowed flash attention, bf16 MFMA.
// Q,K bf16 [B*H][4096][64]; VT bf16 [B*H][64][4096] (pre-transposed).
// Block = 256 thr (4 waves), Q-tile 128 rows (2 x 16-row bands per wave),
// key chunks of 64 (<=6 per tile, window |i-j|<=128), double-buffered K/VT,
// one barrier per chunk, staging issued before compute. Both K and V^T are
// staged via gl_lds16 (linear LDS, swizzled source): no VALU, no conflicts.
// ---------------------------------------------------------------------------
__global__ __launch_bounds__(256) void attn_bf16_k(
    const bf16* __restrict__ Q, const bf16* __restrict__ K,
    const bf16* __restrict__ VTglob, bf16* __restrict__ O) {
    __shared__ bf16 QP[8192];      // Q tile [128][64]; reused as P bands
    __shared__ bf16 Ks[2][4096];   // K chunk [key][64], swizzled, dbuf
    __shared__ bf16 VT[2][4096];   // V^T chunk [d][key], swizzled, dbuf

    const int t = threadIdx.x;
    const int lane = t & 63, wid = t >> 6;
    const int wg = blockIdx.x;
    const int sblk = ((wg & 7) << 6) + (wg >> 3);  // XCD swizzle (512%8==0)
    const int bh = sblk >> 5;
    const int q0 = (sblk & 31) << 7;

    const bf16* Qp = Q + ((size_t)bh << 18);
    const bf16* Kp = K + ((size_t)bh << 18);
    const bf16* VTp = VTglob + ((size_t)bh << 18);  // [64][4096]

#pragma unroll
    for (int i = 0; i < 4; i++) {
        int gid = (i << 8) + t;
        int row = gid >> 3, gs = ((gid & 7) ^ (row & 7)) << 3;
        gl_lds16(Qp + ((size_t)(q0 + row) << 6) + gs, &QP[gid << 3]);
    }
    __syncthreads();

    bf16x8 aq[2][2];
#pragma unroll
    for (int b = 0; b < 2; b++)
#pragma unroll
        for (int ks = 0; ks < 2; ks++)
            aq[b][ks] = frag64(QP, (wid << 5) + (b << 4) + (lane & 15),
                               (ks << 2) + (lane >> 4));

    float mrun[2][4], lrun[2][4];
    f32x4 acc_o[2][4] = {};
#pragma unroll
    for (int b = 0; b < 2; b++)
#pragma unroll
        for (int r = 0; r < 4; r++) { mrun[b][r] = NEGINF; lrun[b][r] = 0.f; }

    const int cstart = (q0 >= 128) ? q0 - 128 : 0;
    const int cend = (q0 + 256 <= N_SEQ) ? q0 + 256 : N_SEQ;
    const int nch = (cend - cstart) >> 6;

    // stage K chunk [key][64] and V^T chunk [d][key], both via gl_lds16
#define STAGE_KV(c0, sb)                                                     \
    {                                                                        \
        _Pragma("unroll") for (int i = 0; i < 2; i++) {                      \
            int gid = (i << 8) + t;                                          \
            int row = gid >> 3, gs = ((gid & 7) ^ (row & 7)) << 3;           \
            gl_lds16(Kp + ((size_t)((c0) + row) << 6) + gs,                  \
                     &Ks[sb][gid << 3]);                                     \
        }                                                                    \
        _Pragma("unroll") for (int i = 0; i < 2; i++) {                      \
            int gid = (i << 8) + t;                                          \
            int row = gid >> 3, gs = ((gid & 7) ^ (row & 7)) << 3;           \
            gl_lds16(VTp + (size_t)row * 4096 + (c0) + gs,                   \
                     &VT[sb][gid << 3]);                                     \
        }                                                                    \
    }

    STAGE_KV(cstart, 0);

    int buf = 0;
    for (int tch = 0; tch < nch; tch++) {
        const int c0 = cstart + (tch << 6);
        __syncthreads();
        if (tch + 1 < nch) STAGE_KV(c0 + 64, buf ^ 1);

        const int rel = c0 - q0;
        const bool masked = (rel != 0) && (rel != 64);

#pragma unroll
        for (int b = 0; b < 2; b++) {
            f32x4 s[4] = {};
#pragma unroll
            for (int ks = 0; ks < 2; ks++) {
                int g = (ks << 2) + (lane >> 4);
#pragma unroll
                for (int ni = 0; ni < 4; ni++) {
                    bf16x8 bk = frag64(&Ks[buf][0], (ni << 4) + (lane & 15), g);
                    s[ni] = __builtin_amdgcn_mfma_f32_16x16x32_bf16(
                        aq[b][ks], bk, s[ni], 0, 0, 0);
                }
            }

            bf16* Pw = &QP[((wid << 1) + b) << 10];
#pragma unroll
            for (int r = 0; r < 4; r++) {
                int rowl = ((lane >> 4) << 2) + r;
                int qi = q0 + (wid << 5) + (b << 4) + rowl;
                float v[4];
                if (masked) {
#pragma unroll
                    for (int ni = 0; ni < 4; ni++) {
                        int kj = c0 + (ni << 4) + (lane & 15);
                        int dd = qi - kj;
                        v[ni] = (dd <= 128 && dd >= -128) ? s[ni][r] * 0.125f
                                                          : NEGINF;
                    }
                } else {
#pragma unroll
                    for (int ni = 0; ni < 4; ni++) v[ni] = s[ni][r] * 0.125f;
                }
                float mx = fmaxf(fmaxf(v[0], v[1]), fmaxf(v[2], v[3]));
#pragma unroll
                for (int off = 1; off < 16; off <<= 1)
                    mx = fmaxf(mx, __shfl_xor(mx, off));
                float mn = fmaxf(mrun[b][r], mx);
                float alpha = __expf(mrun[b][r] - mn);
                float rs = 0.f;
#pragma unroll
                for (int ni = 0; ni < 4; ni++) {
                    float p = __expf(v[ni] - mn);
                    rs += p;
                    int col = (ni << 4) + (lane & 15);
                    Pw[(rowl << 6) + (((col >> 3) ^ (rowl & 7)) << 3) +
                       (col & 7)] = (bf16)p;
                }
#pragma unroll
                for (int off = 1; off < 16; off <<= 1)
                    rs += __shfl_xor(rs, off);
                mrun[b][r] = mn;
                lrun[b][r] = lrun[b][r] * alpha + rs;
#pragma unroll
                for (int nd = 0; nd < 4; nd++) acc_o[b][nd][r] *= alpha;
            }

#pragma unroll
            for (int ks = 0; ks < 2; ks++) {
                int g = (ks << 2) + (lane >> 4);
                bf16x8 pa = frag64(Pw, lane & 15, g);
#pragma unroll
                for (int nd = 0; nd < 4; nd++) {
                    bf16x8 bv = frag64(&VT[buf][0], (nd << 4) + (lane & 15), g);
                    acc_o[b][nd] = __builtin_amdgcn_mfma_f32_16x16x32_bf16(
                        pa, bv, acc_o[b][nd], 0, 0, 0);
                }
            }
        }
        buf ^= 1;
    }
#undef STAGE_KV

    const int bb = bh >> 3, h = bh & 7;
#pragma unroll
    for (int b = 0; b < 2; b++) {
#pragma unroll
        for (int r = 0; r < 4; r++) {
            float inv = 1.f / lrun[b][r];
            int n = q0 + (wid << 5) + (b << 4) + ((lane >> 4) << 2) + r;
#pragma unroll
            for (int nd = 0; nd < 4; nd++) {
                int d = (nd << 4) + (lane & 15);
                O[(((size_t)(bb * 4096 + n)) << 9) + (h << 6) + d] =
                    (bf16)(acc_o[b][nd][r] * inv);
            }
        }
    }
}

extern "C" void kernel_launch(void* const* d_in, const int* in_sizes, int n_in,
                              void* d_out, int out_size, void* d_ws, size_t ws_size,
                              hipStream_t stream) {
    (void)in_sizes; (void)n_in; (void)out_size; (void)ws_size;
    const float* x   = (const float*)d_in[0];
    const float* Wq  = (const float*)d_in[1];
    const float* bq  = (const float*)d_in[2];
    const float* Wk  = (const float*)d_in[3];
    const float* bk  = (const float*)d_in[4];
    const float* Wv  = (const float*)d_in[5];
    const float* bv  = (const float*)d_in[6];
    const float* Wfc = (const float*)d_in[7];
    const float* bfc = (const float*)d_in[8];

    bf16* xb    = (bf16*)d_ws;                       // [8192][512]
    bf16* Wcat  = xb + (size_t)8192 * 512;           // [2048][512]
    float* bcat = (float*)(Wcat + (size_t)2048 * 512);  // [2048]
    bf16* QKVb  = (bf16*)(bcat + 2048);              // Q,K: [2][16][4096][64]
    bf16* VTg   = QKVb + ((size_t)2 << 22);          // V^T: [16][64][4096]
    bf16* Ob    = QKVb + ((size_t)3 << 22);          // [8192][512]

    prep_k<<<2304, 256, 0, stream>>>(x, xb, Wq, bq, Wk, bk, Wv, bv, Wfc, bfc,
                                     Wcat, bcat);

    // fused QKV: C[8192 x 1536]; V third written transposed into VTg
    gemm_bf16_k<0, 128, 12><<<768, 256, 0, stream>>>(xb, Wcat, bcat, QKVb, VTg);

    const bf16* Qb = QKVb;
    const bf16* Kb = QKVb + ((size_t)1 << 22);
    attn_bf16_k<<<512, 256, 0, stream>>>(Qb, Kb, VTg, Ob);

    // fc: C[8192 x 512] fp32
    gemm_bf16_k<1, 64, 8><<<512, 256, 0, stream>>>(
        Ob, Wcat + ((size_t)1536 << 9), bcat + 1536, d_out, nullptr);
}